// Round 19
// baseline (182.666 us; speedup 1.0000x reference)
//
#include <hip/hip_runtime.h>
#include <hip/hip_bf16.h>
#include <math.h>

#define H_DIM 768
#define E_NUM 8
#define DFF   3072
#define T_NUM 2048
#define PAIRS 4096   // T_NUM * top_k(=2), constant by construction

typedef __attribute__((ext_vector_type(8))) short          s16x8;
typedef __attribute__((ext_vector_type(4))) float          f32x4;
typedef __attribute__((ext_vector_type(4))) unsigned int   u32x4;
typedef __attribute__((ext_vector_type(4))) unsigned short u16x4;
typedef __attribute__((ext_vector_type(8))) unsigned short u16x8;

__device__ __forceinline__ unsigned short f2bf(float f) {
  unsigned int u = __builtin_bit_cast(unsigned int, f);
  u += 0x7FFFu + ((u >> 16) & 1u);     // round-to-nearest-even
  return (unsigned short)(u >> 16);
}

__device__ __forceinline__ float bf2f(unsigned short v) {
  unsigned int u = ((unsigned int)v) << 16;
  return __builtin_bit_cast(float, u);
}

// branchless tanh-form GELU: x * sigmoid(1.59577*(x + 0.044715 x^3))
__device__ __forceinline__ float gelu_fast(float x) {
  float t = x * x;
  float a = __builtin_fmaf(t, -0.10294221f, -2.3022082f);
  float w;
  asm("v_exp_f32 %0, %1" : "=v"(w) : "v"(x * a));
  float r;
  float d = 1.0f + w;
  asm("v_rcp_f32 %0, %1" : "=v"(r) : "v"(d));
  return x * r;
}

// ---------------- device bodies ----------------

// routing for 4 tokens (one per wave); no global atomics (r4 lesson)
__device__ __forceinline__ void route_body(
    int rb, const float* __restrict__ x, const float* __restrict__ Wg,
    const float* __restrict__ bg, int* __restrict__ eidx, float* __restrict__ ew) {
  int wave = threadIdx.x >> 6, lane = threadIdx.x & 63;
  int t = rb * 4 + wave;
  const float* xr = x + (size_t)t * H_DIM;
  float acc[E_NUM];
#pragma unroll
  for (int e = 0; e < E_NUM; ++e) acc[e] = 0.f;
#pragma unroll
  for (int i = 0; i < H_DIM / 64; ++i) {
    int h = i * 64 + lane;
    float xv = xr[h];
    f32x4 w0 = *(const f32x4*)&Wg[h * 8];
    f32x4 w1 = *(const f32x4*)&Wg[h * 8 + 4];
    acc[0] += xv * w0[0]; acc[1] += xv * w0[1];
    acc[2] += xv * w0[2]; acc[3] += xv * w0[3];
    acc[4] += xv * w1[0]; acc[5] += xv * w1[1];
    acc[6] += xv * w1[2]; acc[7] += xv * w1[3];
  }
#pragma unroll
  for (int e = 0; e < E_NUM; ++e) {
#pragma unroll
    for (int off = 32; off > 0; off >>= 1) acc[e] += __shfl_xor(acc[e], off);
  }
  if (lane == 0) {
    float l[E_NUM];
#pragma unroll
    for (int e = 0; e < E_NUM; ++e) l[e] = acc[e] + bg[e];
    int i0 = 0;
#pragma unroll
    for (int e = 1; e < E_NUM; ++e) if (l[e] > l[i0]) i0 = e;
    int i1 = (i0 == 0) ? 1 : 0;
#pragma unroll
    for (int e = 0; e < E_NUM; ++e) if (e != i0 && l[e] > l[i1]) i1 = e;
    float d  = expf(l[i1] - l[i0]);
    eidx[2 * t]     = i0;
    eidx[2 * t + 1] = i1;
    ew[2 * t]       = 1.f / (1.f + d);
    ew[2 * t + 1]   = d / (1.f + d);
  }
}

// one 128x128 transpose-cast tile (r18-verified): [E][R][C] fp32 -> [E][C][R] bf16
__device__ __forceinline__ void transpose_body(
    int tb, const float* __restrict__ in, unsigned short* __restrict__ out,
    int R, int C) {
  __shared__ unsigned short tile[128][136];
  int tpe = (R / 128) * (C / 128);
  int e   = tb / tpe;
  int rem = tb % tpe;
  int bx  = rem % (C / 128);
  int by  = rem / (C / 128);
  int c0 = bx * 128, r0 = by * 128;
  const float* ip = in + (size_t)e * R * C;
  unsigned short* op = out + (size_t)e * R * C;
  int tid = threadIdx.x;

  int tx = tid & 31, ty = tid >> 5;
#pragma unroll
  for (int i = 0; i < 16; ++i) {
    int r = i * 8 + ty;
    f32x4 v = *(const f32x4*)&ip[(size_t)(r0 + r) * C + c0 + tx * 4];
    u16x4 o;
    o[0] = f2bf(v[0]); o[1] = f2bf(v[1]); o[2] = f2bf(v[2]); o[3] = f2bf(v[3]);
    int cs = (tx * 4) ^ (((r >> 3) & 7) << 2);   // 4-aligned XOR swizzle
    *(u16x4*)&tile[r][cs] = o;
  }
  __syncthreads();

  int rb2 = (tid & 15) * 8;
  int key = (tid & 7) << 2;
#pragma unroll
  for (int p = 0; p < 8; ++p) {
    int c = p * 16 + (tid >> 4);
    int cs = c ^ key;
    u16x8 o;
#pragma unroll
    for (int j = 0; j < 8; ++j) o[j] = tile[rb2 + j][cs];
    *(u16x8*)&op[(size_t)(c0 + c) * R + r0 + rb2] = o;
  }
}

// ---------------- kernels ----------------

// ONE prep launch: route (512) || transpose W1 (1152) || transpose W2 (1152).
// (Do NOT fuse GEMMs with streaming work — r10/r16 lessons.)
__global__ __launch_bounds__(256) void k_prep(
    const float* __restrict__ x, const float* __restrict__ Wg,
    const float* __restrict__ bg, int* __restrict__ eidx, float* __restrict__ ew,
    const float* __restrict__ W1, unsigned short* __restrict__ Wb1,
    const float* __restrict__ W2, unsigned short* __restrict__ Wb2) {
  constexpr int NR  = T_NUM / 4;                               // 512
  constexpr int NT1 = E_NUM * (H_DIM / 128) * (DFF / 128);     // 1152
  int b = blockIdx.x;
  if (b < NR)            route_body(b, x, Wg, bg, eidx, ew);
  else if (b < NR + NT1) transpose_body(b - NR, W1, Wb1, H_DIM, DFF);
  else                   transpose_body(b - NR - NT1, W2, Wb2, DFF, H_DIM);
}

// Single block: LDS histogram -> prefix -> LDS-atomic scatter (no global atomics).
__global__ __launch_bounds__(256) void k_build(
    const int* __restrict__ eidx, int* __restrict__ counts, int* __restrict__ offsets,
    int* __restrict__ tok_of, int* __restrict__ slot_of) {
  __shared__ int cnt[E_NUM];
  __shared__ int cur[E_NUM];
  int tid = threadIdx.x;
  if (tid < E_NUM) cnt[tid] = 0;
  __syncthreads();
#pragma unroll
  for (int i = 0; i < PAIRS / 256; ++i)
    atomicAdd(&cnt[eidx[i * 256 + tid]], 1);
  __syncthreads();
  if (tid == 0) {
    int s = 0;
    for (int e = 0; e < E_NUM; ++e) { cur[e] = s; s += cnt[e]; }
  }
  __syncthreads();
  if (tid < E_NUM) { counts[tid] = cnt[tid]; offsets[tid] = cur[tid]; }
#pragma unroll
  for (int i = 0; i < PAIRS / 256; ++i) {
    int p = i * 256 + tid;
    int s = atomicAdd(&cur[eidx[p]], 1);
    tok_of[s] = p >> 1;
    slot_of[p] = s;
  }
}

// standalone gather: 16 slots per block (4 waves x 4), 6.3 MB total — tiny
__global__ __launch_bounds__(256) void k_gather(
    const float* __restrict__ x, const int* __restrict__ tok_of,
    unsigned short* __restrict__ Xg) {
  int wave = threadIdx.x >> 6, lane = threadIdx.x & 63;
#pragma unroll
  for (int j = 0; j < 4; ++j) {
    int s = blockIdx.x * 16 + j * 4 + wave;
    int t = tok_of[s];
    const f32x4* xr = (const f32x4*)(x + (size_t)t * H_DIM);
    u16x4* orow = (u16x4*)(Xg + (size_t)s * H_DIM);
#pragma unroll
    for (int i = 0; i < H_DIM / 256; ++i) {
      f32x4 v = xr[i * 64 + lane];
      u16x4 o;
      o[0] = f2bf(v[0]); o[1] = f2bf(v[1]); o[2] = f2bf(v[2]); o[3] = f2bf(v[3]);
      orow[i * 64 + lane] = o;
    }
  }
}

// r19 GEMM: 128x128 tile, 4 waves (2x2 of 64x64), BK=64 — A staged via the
// r6-verified global_load_lds dbuf path (now 32 KB LDS -> 3+ blocks/CU);
// B-fragments loaded GLOBAL->REGISTER directly (each fragment is wave-private;
// addresses identical to the verified ds_read path minus the swizzle layer).
// vmcnt: per step in flight = A(s+1) 4 lds-loads + B(s+1) 8 reg-loads ->
// vmcnt(12) retires tile s; tail drains 0. Full unroll keeps B-reg buffers
// statically indexed (rule #20). Decode: nt fastest, e mid, part, mt outer.
template <int KTOT, int NT, int NSPLIT, int MT_MAX, bool GELU_OUT>
__global__ __launch_bounds__(256) void k_gemm(
    const unsigned short* __restrict__ A, const unsigned short* __restrict__ B,
    const float* __restrict__ bias, void* __restrict__ C,
    const int* __restrict__ counts, const int* __restrict__ offsets) {
  constexpr int NDIM  = NT * 128;
  constexpr int KLEN  = KTOT / NSPLIT;
  constexpr int NSTEP = KLEN / 64;
  int l = blockIdx.x;
  int nt = l % NT;  l /= NT;
  int e  = l & 7;   l >>= 3;
  int part = l % NSPLIT;
  int mt = l / NSPLIT;
  int Me = counts[e];
  if (mt * 128 >= Me) return;
  int seg = offsets[e];

  __shared__ __align__(16) unsigned short Al[2][128 * 64];   // A only: 32 KB

  int tid  = threadIdx.x;
  int lane = tid & 63;
  int wave = tid >> 6;
  int wm = wave >> 1, wn = wave & 1;   // 2x2 waves, 64x64 each

  int sr   = tid >> 3;                               // staging row 0..31 per pass
  int scl  = (tid & 7) * 8;                          // linear LDS col (elems)
  int scs  = (((tid & 7) ^ (sr & 7)) * 8);           // swizzled global source col
  int rxor = (lane & 7) << 3;                        // read-side XOR (elems)

  f32x4 acc[4][4];
#pragma unroll
  for (int m = 0; m < 4; ++m)
#pragma unroll
    for (int n = 0; n < 4; ++n) acc[m][n] = (f32x4){0.f, 0.f, 0.f, 0.f};

  const unsigned short* Abase = A + (size_t)seg * KTOT;
  // per-lane B fragment base: row = nt*128 + wn*64 + (lane&15), k-sub = (lane>>4)*8
  const unsigned short* Bfrag = B + (size_t)e * NDIM * KTOT
      + (size_t)(nt * 128 + wn * 64 + (lane & 15)) * KTOT + ((lane >> 4) * 8);
  const int kbeg = part * KLEN;

  auto stage = [&](int bb, int k0) {   // 4 global_load_lds per thread (A only)
#pragma unroll
    for (int j = 0; j < 4; ++j) {
      int row = j * 32 + sr;
      int r = mt * 128 + row;
      r = (r < Me) ? r : (Me - 1);     // clamp (dup last row; stores predicated)
      const unsigned short* gp = Abase + (size_t)r * KTOT + k0 + scs;
      __builtin_amdgcn_global_load_lds(
          (__attribute__((address_space(1))) void*)gp,
          (__attribute__((address_space(3))) void*)&Al[bb][row * 64 + scl], 16, 0, 0);
    }
  };

  auto loadB = [&](s16x8 (&br)[4][2], int k0) {   // 8 16B reg loads per thread
#pragma unroll
    for (int n = 0; n < 4; ++n)
#pragma unroll
      for (int kk = 0; kk < 2; ++kk) {
        u32x4 v = *(const u32x4*)(Bfrag + (size_t)(n * 16) * KTOT + k0 + kk * 32);
        br[n][kk] = __builtin_bit_cast(s16x8, v);
      }
  };

  auto compute = [&](int bb, s16x8 (&br)[4][2]) {
#pragma unroll
    for (int kk = 0; kk < 2; ++kk) {
      int ko = kk * 32 + (lane >> 4) * 8;
      s16x8 af[4];
#pragma unroll
      for (int m = 0; m < 4; ++m) {
        int row = wm * 64 + m * 16 + (lane & 15);
        u32x4 v = *(const u32x4*)&Al[bb][(row * 64 + ko) ^ rxor];
        af[m] = __builtin_bit_cast(s16x8, v);
      }
#pragma unroll
      for (int m = 0; m < 4; ++m)
#pragma unroll
        for (int n = 0; n < 4; ++n)
          acc[m][n] = __builtin_amdgcn_mfma_f32_16x16x32_bf16(af[m], br[n][kk], acc[m][n], 0, 0, 0);
    }
  };

  s16x8 br0[4][2], br1[4][2];
  stage(0, kbeg);       loadB(br0, kbeg);
  stage(1, kbeg + 64);  loadB(br1, kbeg + 64);
#pragma unroll
  for (int s = 0; s < NSTEP; ++s) {
    // retire tile s's A(4 lds)+B(8 reg) loads; keep tile s+1's 12 in flight
    if (s + 1 < NSTEP) asm volatile("s_waitcnt vmcnt(12)" ::: "memory");
    else               asm volatile("s_waitcnt vmcnt(0)" ::: "memory");
    __builtin_amdgcn_s_barrier();      // all waves' A(s) landed in LDS
    if (s & 1) compute(1, br1); else compute(0, br0);
    if (s + 2 < NSTEP) {
      __builtin_amdgcn_s_barrier();    // all waves done READING Al[s&1]
      stage(s & 1, kbeg + (s + 2) * 64);
      if (s & 1) loadB(br1, kbeg + (s + 2) * 64);
      else       loadB(br0, kbeg + (s + 2) * 64);
    }
  }

  // epilogue: C/D layout col = lane&15, row = (lane>>4)*4 + reg
  int rbase = mt * 128 + wm * 64;
  int cbase = nt * 128 + wn * 64;
#pragma unroll
  for (int m = 0; m < 4; ++m) {
#pragma unroll
    for (int n = 0; n < 4; ++n) {
      int col = cbase + n * 16 + (lane & 15);
      float bv = GELU_OUT ? bias[e * NDIM + col] : 0.f;
#pragma unroll
      for (int r = 0; r < 4; ++r) {
        int row = rbase + m * 16 + (lane >> 4) * 4 + r;
        if (row < Me) {
          float v = acc[m][n][r] + bv;
          size_t idx = ((size_t)part * PAIRS + seg + row) * NDIM + col;
          if constexpr (GELU_OUT) {
            ((unsigned short*)C)[idx] = f2bf(gelu_fast(v));
          } else {
            ((unsigned short*)C)[idx] = f2bf(v);   // bf16 partial; bias in combine
          }
        }
      }
    }
  }
}

// out[t] = w0*(sum_p P[p][s0] + b2[e0]) + w1*(sum_p P[p][s1] + b2[e1]); P is bf16
template <int NSPLIT>
__global__ void k_combine(const unsigned short* __restrict__ P, const int* __restrict__ slot_of,
                          const int* __restrict__ eidx, const float* __restrict__ ew,
                          const float* __restrict__ b2, float* __restrict__ out) {
  int t = blockIdx.x;
  int i = threadIdx.x;  // 192 threads * 4 floats = 768
  int s0 = slot_of[2 * t], s1 = slot_of[2 * t + 1];
  int e0 = eidx[2 * t],    e1 = eidx[2 * t + 1];
  float w0 = ew[2 * t], w1 = ew[2 * t + 1];
  f32x4 a = *(const f32x4*)&b2[e0 * H_DIM + i * 4];
  f32x4 c = *(const f32x4*)&b2[e1 * H_DIM + i * 4];
#pragma unroll
  for (int p = 0; p < NSPLIT; ++p) {
    u16x4 va = *(const u16x4*)&P[((size_t)p * PAIRS + s0) * H_DIM + i * 4];
    u16x4 vb = *(const u16x4*)&P[((size_t)p * PAIRS + s1) * H_DIM + i * 4];
#pragma unroll
    for (int j = 0; j < 4; ++j) { a[j] += bf2f(va[j]); c[j] += bf2f(vb[j]); }
  }
  f32x4 o;
  o[0] = w0 * a[0] + w1 * c[0];
  o[1] = w0 * a[1] + w1 * c[1];
  o[2] = w0 * a[2] + w1 * c[2];
  o[3] = w0 * a[3] + w1 * c[3];
  ((f32x4*)(out + (size_t)t * H_DIM))[i] = o;
}

extern "C" void kernel_launch(void* const* d_in, const int* in_sizes, int n_in,
                              void* d_out, int out_size, void* d_ws, size_t ws_size,
                              hipStream_t stream) {
  (void)in_sizes; (void)n_in; (void)out_size;
  const float* x  = (const float*)d_in[0];
  const float* Wg = (const float*)d_in[1];
  const float* bg = (const float*)d_in[2];
  const float* W1 = (const float*)d_in[3];
  const float* b1 = (const float*)d_in[4];
  const float* W2 = (const float*)d_in[5];
  const float* b2 = (const float*)d_in[6];
  float* out = (float*)d_out;

  char* w = (char*)d_ws;
  size_t off = 0;
  auto take = [&](size_t n) { void* p = w + off; off = (off + n + 255) & ~(size_t)255; return p; };
  int*   ctrl    = (int*)  take(64 * sizeof(int));   // [0..7] counts, [8..15] offsets
  int*   eidx    = (int*)  take(PAIRS * sizeof(int));
  float* ew      = (float*)take(PAIRS * sizeof(float));
  int*   slot_of = (int*)  take(PAIRS * sizeof(int));
  int*   tok_of  = (int*)  take(PAIRS * sizeof(int));
  unsigned short* Xg   = (unsigned short*)take((size_t)PAIRS * H_DIM * 2);
  unsigned short* Hmid = (unsigned short*)take((size_t)PAIRS * DFF * 2);
  unsigned short* P    = (unsigned short*)take((size_t)2 * PAIRS * H_DIM * 2);
  unsigned short* Wb1  = (unsigned short*)take((size_t)E_NUM * H_DIM * DFF * 2);
  unsigned short* Wb2  = (unsigned short*)take((size_t)E_NUM * H_DIM * DFF * 2);
  if (off > ws_size) return;   // ~120 MB; r10/r12 proved >=132 MB available

  int* counts  = ctrl;
  int* offsets = ctrl + 8;

  // prep: route || T1 || T2 in one launch: 512 + 1152 + 1152 = 2816 blocks
  k_prep<<<T_NUM / 4 + 2 * E_NUM * (H_DIM / 128) * (DFF / 128), 256, 0, stream>>>(
      x, Wg, bg, eidx, ew, W1, Wb1, W2, Wb2);
  k_build<<<1, 256, 0, stream>>>(eidx, counts, offsets, tok_of, slot_of);
  k_gather<<<PAIRS / 16, 256, 0, stream>>>(x, tok_of, Xg);

  // GEMM1: 24 nt * 8 e * 6 mt = 1152 blocks (MT_MAX=6 covers Me<=768, 12-sigma)
  k_gemm<H_DIM, DFF / 128, 1, 6, true><<<(DFF / 128) * E_NUM * 6, 256, 0, stream>>>(
      Xg, Wb1, b1, Hmid, counts, offsets);

  // GEMM2: split-K=2, MT_MAX=6 -> 6 nt * 8 e * 2 part * 6 mt = 576 blocks
  k_gemm<DFF, H_DIM / 128, 2, 6, false><<<(H_DIM / 128) * E_NUM * 2 * 6, 256, 0, stream>>>(
      Hmid, Wb2, b2, P, counts, offsets);
  k_combine<2><<<T_NUM, 192, 0, stream>>>(P, slot_of, eidx, ew, b2, out);
}

// Round 20
// 138.105 us; speedup vs baseline: 1.3227x; 1.3227x over previous
//
#include <hip/hip_runtime.h>
#include <hip/hip_bf16.h>
#include <math.h>

#define H_DIM 768
#define E_NUM 8
#define DFF   3072
#define T_NUM 2048
#define PAIRS 4096   // T_NUM * top_k(=2), constant by construction

typedef __attribute__((ext_vector_type(8))) short          s16x8;
typedef __attribute__((ext_vector_type(4))) float          f32x4;
typedef __attribute__((ext_vector_type(4))) unsigned int   u32x4;
typedef __attribute__((ext_vector_type(4))) unsigned short u16x4;
typedef __attribute__((ext_vector_type(8))) unsigned short u16x8;

__device__ __forceinline__ unsigned short f2bf(float f) {
  unsigned int u = __builtin_bit_cast(unsigned int, f);
  u += 0x7FFFu + ((u >> 16) & 1u);     // round-to-nearest-even
  return (unsigned short)(u >> 16);
}

__device__ __forceinline__ float bf2f(unsigned short v) {
  unsigned int u = ((unsigned int)v) << 16;
  return __builtin_bit_cast(float, u);
}

// branchless tanh-form GELU: x * sigmoid(1.59577*(x + 0.044715 x^3))
__device__ __forceinline__ float gelu_fast(float x) {
  float t = x * x;
  float a = __builtin_fmaf(t, -0.10294221f, -2.3022082f);
  float w;
  asm("v_exp_f32 %0, %1" : "=v"(w) : "v"(x * a));
  float r;
  float d = 1.0f + w;
  asm("v_rcp_f32 %0, %1" : "=v"(r) : "v"(d));
  return x * r;
}

// ---------------- device bodies ----------------

// routing for 4 tokens (one per wave); no global atomics (r4 lesson)
__device__ __forceinline__ void route_body(
    int rb, const float* __restrict__ x, const float* __restrict__ Wg,
    const float* __restrict__ bg, int* __restrict__ eidx, float* __restrict__ ew) {
  int wave = threadIdx.x >> 6, lane = threadIdx.x & 63;
  int t = rb * 4 + wave;
  const float* xr = x + (size_t)t * H_DIM;
  float acc[E_NUM];
#pragma unroll
  for (int e = 0; e < E_NUM; ++e) acc[e] = 0.f;
#pragma unroll
  for (int i = 0; i < H_DIM / 64; ++i) {
    int h = i * 64 + lane;
    float xv = xr[h];
    f32x4 w0 = *(const f32x4*)&Wg[h * 8];
    f32x4 w1 = *(const f32x4*)&Wg[h * 8 + 4];
    acc[0] += xv * w0[0]; acc[1] += xv * w0[1];
    acc[2] += xv * w0[2]; acc[3] += xv * w0[3];
    acc[4] += xv * w1[0]; acc[5] += xv * w1[1];
    acc[6] += xv * w1[2]; acc[7] += xv * w1[3];
  }
#pragma unroll
  for (int e = 0; e < E_NUM; ++e) {
#pragma unroll
    for (int off = 32; off > 0; off >>= 1) acc[e] += __shfl_xor(acc[e], off);
  }
  if (lane == 0) {
    float l[E_NUM];
#pragma unroll
    for (int e = 0; e < E_NUM; ++e) l[e] = acc[e] + bg[e];
    int i0 = 0;
#pragma unroll
    for (int e = 1; e < E_NUM; ++e) if (l[e] > l[i0]) i0 = e;
    int i1 = (i0 == 0) ? 1 : 0;
#pragma unroll
    for (int e = 0; e < E_NUM; ++e) if (e != i0 && l[e] > l[i1]) i1 = e;
    float d  = expf(l[i1] - l[i0]);
    eidx[2 * t]     = i0;
    eidx[2 * t + 1] = i1;
    ew[2 * t]       = 1.f / (1.f + d);
    ew[2 * t + 1]   = d / (1.f + d);
  }
}

// one 128x128 transpose-cast tile: [E][R][C] fp32 -> [E][C][R] bf16.
// r18 coalescing: reads 512B-contiguous per 32 lanes, writes 256B-contiguous
// u16x8 per 16 lanes. LDS [128][136] + XOR swizzle c' = c ^ (((r>>3)&7)<<2)
// (involution on store+load -> correct by construction).
__device__ __forceinline__ void transpose_body(
    int tb, const float* __restrict__ in, unsigned short* __restrict__ out,
    int R, int C) {
  __shared__ unsigned short tile[128][136];
  int tpe = (R / 128) * (C / 128);
  int e   = tb / tpe;
  int rem = tb % tpe;
  int bx  = rem % (C / 128);
  int by  = rem / (C / 128);
  int c0 = bx * 128, r0 = by * 128;
  const float* ip = in + (size_t)e * R * C;
  unsigned short* op = out + (size_t)e * R * C;
  int tid = threadIdx.x;

  // read: 16 passes x 8 rows; each row = 32 lanes x f32x4 = 512B contiguous
  int tx = tid & 31, ty = tid >> 5;
#pragma unroll
  for (int i = 0; i < 16; ++i) {
    int r = i * 8 + ty;
    f32x4 v = *(const f32x4*)&ip[(size_t)(r0 + r) * C + c0 + tx * 4];
    u16x4 o;
    o[0] = f2bf(v[0]); o[1] = f2bf(v[1]); o[2] = f2bf(v[2]); o[3] = f2bf(v[3]);
    int cs = (tx * 4) ^ (((r >> 3) & 7) << 2);   // 4-aligned XOR swizzle
    *(u16x4*)&tile[r][cs] = o;
  }
  __syncthreads();

  // write: 8 passes x 16 output rows; each row = 16 lanes x u16x8 = 256B contig
  int rb2 = (tid & 15) * 8;
  int key = (tid & 7) << 2;                      // ((r>>3)&7)<<2, r>>3 == tid&15
#pragma unroll
  for (int p = 0; p < 8; ++p) {
    int c = p * 16 + (tid >> 4);
    int cs = c ^ key;
    u16x8 o;
#pragma unroll
    for (int j = 0; j < 8; ++j) o[j] = tile[rb2 + j][cs];
    *(u16x8*)&op[(size_t)(c0 + c) * R + r0 + rb2] = o;
  }
}

// ---------------- kernels ----------------

// ONE prep launch: route (512) || transpose W1 (1152) || transpose W2 (1152).
// (Do NOT fuse GEMMs with streaming work — r10/r16 lessons.)
__global__ __launch_bounds__(256) void k_prep(
    const float* __restrict__ x, const float* __restrict__ Wg,
    const float* __restrict__ bg, int* __restrict__ eidx, float* __restrict__ ew,
    const float* __restrict__ W1, unsigned short* __restrict__ Wb1,
    const float* __restrict__ W2, unsigned short* __restrict__ Wb2) {
  constexpr int NR  = T_NUM / 4;                               // 512
  constexpr int NT1 = E_NUM * (H_DIM / 128) * (DFF / 128);     // 1152
  int b = blockIdx.x;
  if (b < NR)            route_body(b, x, Wg, bg, eidx, ew);
  else if (b < NR + NT1) transpose_body(b - NR, W1, Wb1, H_DIM, DFF);
  else                   transpose_body(b - NR - NT1, W2, Wb2, DFF, H_DIM);
}

// Single block: LDS histogram -> prefix -> LDS-atomic scatter (no global atomics).
__global__ __launch_bounds__(256) void k_build(
    const int* __restrict__ eidx, int* __restrict__ counts, int* __restrict__ offsets,
    int* __restrict__ tok_of, int* __restrict__ slot_of) {
  __shared__ int cnt[E_NUM];
  __shared__ int cur[E_NUM];
  int tid = threadIdx.x;
  if (tid < E_NUM) cnt[tid] = 0;
  __syncthreads();
#pragma unroll
  for (int i = 0; i < PAIRS / 256; ++i)
    atomicAdd(&cnt[eidx[i * 256 + tid]], 1);
  __syncthreads();
  if (tid == 0) {
    int s = 0;
    for (int e = 0; e < E_NUM; ++e) { cur[e] = s; s += cnt[e]; }
  }
  __syncthreads();
  if (tid < E_NUM) { counts[tid] = cnt[tid]; offsets[tid] = cur[tid]; }
#pragma unroll
  for (int i = 0; i < PAIRS / 256; ++i) {
    int p = i * 256 + tid;
    int s = atomicAdd(&cur[eidx[p]], 1);
    tok_of[s] = p >> 1;
    slot_of[p] = s;
  }
}

// standalone gather: 16 slots per block (4 waves x 4), 6.3 MB total — tiny
__global__ __launch_bounds__(256) void k_gather(
    const float* __restrict__ x, const int* __restrict__ tok_of,
    unsigned short* __restrict__ Xg) {
  int wave = threadIdx.x >> 6, lane = threadIdx.x & 63;
#pragma unroll
  for (int j = 0; j < 4; ++j) {
    int s = blockIdx.x * 16 + j * 4 + wave;
    int t = tok_of[s];
    const f32x4* xr = (const f32x4*)(x + (size_t)t * H_DIM);
    u16x4* orow = (u16x4*)(Xg + (size_t)s * H_DIM);
#pragma unroll
    for (int i = 0; i < H_DIM / 256; ++i) {
      f32x4 v = xr[i * 64 + lane];
      u16x4 o;
      o[0] = f2bf(v[0]); o[1] = f2bf(v[1]); o[2] = f2bf(v[2]); o[3] = f2bf(v[3]);
      orow[i * 64 + lane] = o;
    }
  }
}

// r6/r13/r15/r18-verified GEMM (floor of 10 structural variants, 46 us):
// 128x128 tile, 4 waves (2x2 of 64x64), BK=64, double-buffered static 64 KB
// LDS (2 blocks/CU) with counted vmcnt(8) — current tile retired, next tile's
// 8 loads stay in flight across the barrier. T2 swizzle (conflicts=0): linear
// LDS dest + permuted global source col + XOR'd ds_read. Decode: nt fastest,
// e mid, part, mt outermost (balanced, no XCD pinning — r8 lesson).
// Cooperative LDS staging of BOTH operands is essential (r19: B-in-reg loses
// coalescing -> 64x16B scattered transactions, +56% time).
template <int KTOT, int NT, int NSPLIT, int MT_MAX, bool GELU_OUT>
__global__ __launch_bounds__(256) void k_gemm(
    const unsigned short* __restrict__ A, const unsigned short* __restrict__ B,
    const float* __restrict__ bias, void* __restrict__ C,
    const int* __restrict__ counts, const int* __restrict__ offsets) {
  constexpr int NDIM  = NT * 128;
  constexpr int KLEN  = KTOT / NSPLIT;
  constexpr int NSTEP = KLEN / 64;
  int l = blockIdx.x;
  int nt = l % NT;  l /= NT;
  int e  = l & 7;   l >>= 3;
  int part = l % NSPLIT;
  int mt = l / NSPLIT;
  int Me = counts[e];
  if (mt * 128 >= Me) return;
  int seg = offsets[e];

  __shared__ __align__(16) unsigned short Al[2][128 * 64];
  __shared__ __align__(16) unsigned short Bl[2][128 * 64];

  int tid  = threadIdx.x;
  int lane = tid & 63;
  int wave = tid >> 6;
  int wm = wave >> 1, wn = wave & 1;   // 2x2 waves, 64x64 each

  int sr   = tid >> 3;                               // staging row 0..31 per pass
  int scl  = (tid & 7) * 8;                          // linear LDS col (elems)
  int scs  = (((tid & 7) ^ (sr & 7)) * 8);           // swizzled global source col
  int rxor = (lane & 7) << 3;                        // read-side XOR (elems)

  f32x4 acc[4][4];
#pragma unroll
  for (int m = 0; m < 4; ++m)
#pragma unroll
    for (int n = 0; n < 4; ++n) acc[m][n] = (f32x4){0.f, 0.f, 0.f, 0.f};

  const unsigned short* Abase = A + (size_t)seg * KTOT;
  const unsigned short* Bbase = B + (size_t)e * NDIM * KTOT + (size_t)(nt * 128) * KTOT;
  const int kbeg = part * KLEN;

  auto stage = [&](int bb, int k0) {   // 8 global_load_lds per thread
#pragma unroll
    for (int j = 0; j < 4; ++j) {
      int row = j * 32 + sr;
      int r = mt * 128 + row;
      r = (r < Me) ? r : (Me - 1);     // clamp (dup last row; stores predicated)
      const unsigned short* gp = Abase + (size_t)r * KTOT + k0 + scs;
      __builtin_amdgcn_global_load_lds(
          (__attribute__((address_space(1))) void*)gp,
          (__attribute__((address_space(3))) void*)&Al[bb][row * 64 + scl], 16, 0, 0);
    }
#pragma unroll
    for (int j = 0; j < 4; ++j) {
      int row = j * 32 + sr;
      const unsigned short* gp = Bbase + (size_t)row * KTOT + k0 + scs;
      __builtin_amdgcn_global_load_lds(
          (__attribute__((address_space(1))) void*)gp,
          (__attribute__((address_space(3))) void*)&Bl[bb][row * 64 + scl], 16, 0, 0);
    }
  };

  auto compute = [&](int bb) {
#pragma unroll
    for (int kk = 0; kk < 2; ++kk) {
      int ko = kk * 32 + (lane >> 4) * 8;
      s16x8 af[4], bfr[4];
#pragma unroll
      for (int m = 0; m < 4; ++m) {
        int row = wm * 64 + m * 16 + (lane & 15);
        u32x4 v = *(const u32x4*)&Al[bb][(row * 64 + ko) ^ rxor];
        af[m] = __builtin_bit_cast(s16x8, v);
      }
#pragma unroll
      for (int n = 0; n < 4; ++n) {
        int row = wn * 64 + n * 16 + (lane & 15);
        u32x4 v = *(const u32x4*)&Bl[bb][(row * 64 + ko) ^ rxor];
        bfr[n] = __builtin_bit_cast(s16x8, v);
      }
#pragma unroll
      for (int m = 0; m < 4; ++m)
#pragma unroll
        for (int n = 0; n < 4; ++n)
          acc[m][n] = __builtin_amdgcn_mfma_f32_16x16x32_bf16(af[m], bfr[n], acc[m][n], 0, 0, 0);
    }
  };

  stage(0, kbeg);
  stage(1, kbeg + 64);
  int cur = 0;
#pragma unroll
  for (int s = 0; s < NSTEP; ++s) {
    // retire exactly the current tile's 8 loads; keep next tile's in flight
    if (s + 1 < NSTEP) asm volatile("s_waitcnt vmcnt(8)" ::: "memory");
    else               asm volatile("s_waitcnt vmcnt(0)" ::: "memory");
    __builtin_amdgcn_s_barrier();      // all waves' cur-tile loads landed
    compute(cur);                      // ds_read + MFMA (compiler handles lgkm)
    if (s + 2 < NSTEP) {
      __builtin_amdgcn_s_barrier();    // all waves done READING cur
      stage(cur, kbeg + (s + 2) * 64); // overwrite cur with tile s+2
    }
    cur ^= 1;
  }

  // epilogue: C/D layout col = lane&15, row = (lane>>4)*4 + reg
  int rbase = mt * 128 + wm * 64;
  int cbase = nt * 128 + wn * 64;
#pragma unroll
  for (int m = 0; m < 4; ++m) {
#pragma unroll
    for (int n = 0; n < 4; ++n) {
      int col = cbase + n * 16 + (lane & 15);
      float bv = GELU_OUT ? bias[e * NDIM + col] : 0.f;
#pragma unroll
      for (int r = 0; r < 4; ++r) {
        int row = rbase + m * 16 + (lane >> 4) * 4 + r;
        if (row < Me) {
          float v = acc[m][n][r] + bv;
          size_t idx = ((size_t)part * PAIRS + seg + row) * NDIM + col;
          if constexpr (GELU_OUT) {
            ((unsigned short*)C)[idx] = f2bf(gelu_fast(v));
          } else {
            ((unsigned short*)C)[idx] = f2bf(v);   // bf16 partial; bias in combine
          }
        }
      }
    }
  }
}

// out[t] = w0*(sum_p P[p][s0] + b2[e0]) + w1*(sum_p P[p][s1] + b2[e1]); P is bf16
template <int NSPLIT>
__global__ void k_combine(const unsigned short* __restrict__ P, const int* __restrict__ slot_of,
                          const int* __restrict__ eidx, const float* __restrict__ ew,
                          const float* __restrict__ b2, float* __restrict__ out) {
  int t = blockIdx.x;
  int i = threadIdx.x;  // 192 threads * 4 floats = 768
  int s0 = slot_of[2 * t], s1 = slot_of[2 * t + 1];
  int e0 = eidx[2 * t],    e1 = eidx[2 * t + 1];
  float w0 = ew[2 * t], w1 = ew[2 * t + 1];
  f32x4 a = *(const f32x4*)&b2[e0 * H_DIM + i * 4];
  f32x4 c = *(const f32x4*)&b2[e1 * H_DIM + i * 4];
#pragma unroll
  for (int p = 0; p < NSPLIT; ++p) {
    u16x4 va = *(const u16x4*)&P[((size_t)p * PAIRS + s0) * H_DIM + i * 4];
    u16x4 vb = *(const u16x4*)&P[((size_t)p * PAIRS + s1) * H_DIM + i * 4];
#pragma unroll
    for (int j = 0; j < 4; ++j) { a[j] += bf2f(va[j]); c[j] += bf2f(vb[j]); }
  }
  f32x4 o;
  o[0] = w0 * a[0] + w1 * c[0];
  o[1] = w0 * a[1] + w1 * c[1];
  o[2] = w0 * a[2] + w1 * c[2];
  o[3] = w0 * a[3] + w1 * c[3];
  ((f32x4*)(out + (size_t)t * H_DIM))[i] = o;
}

extern "C" void kernel_launch(void* const* d_in, const int* in_sizes, int n_in,
                              void* d_out, int out_size, void* d_ws, size_t ws_size,
                              hipStream_t stream) {
  (void)in_sizes; (void)n_in; (void)out_size;
  const float* x  = (const float*)d_in[0];
  const float* Wg = (const float*)d_in[1];
  const float* bg = (const float*)d_in[2];
  const float* W1 = (const float*)d_in[3];
  const float* b1 = (const float*)d_in[4];
  const float* W2 = (const float*)d_in[5];
  const float* b2 = (const float*)d_in[6];
  float* out = (float*)d_out;

  char* w = (char*)d_ws;
  size_t off = 0;
  auto take = [&](size_t n) { void* p = w + off; off = (off + n + 255) & ~(size_t)255; return p; };
  int*   ctrl    = (int*)  take(64 * sizeof(int));   // [0..7] counts, [8..15] offsets
  int*   eidx    = (int*)  take(PAIRS * sizeof(int));
  float* ew      = (float*)take(PAIRS * sizeof(float));
  int*   slot_of = (int*)  take(PAIRS * sizeof(int));
  int*   tok_of  = (int*)  take(PAIRS * sizeof(int));
  unsigned short* Xg   = (unsigned short*)take((size_t)PAIRS * H_DIM * 2);
  unsigned short* Hmid = (unsigned short*)take((size_t)PAIRS * DFF * 2);
  unsigned short* P    = (unsigned short*)take((size_t)2 * PAIRS * H_DIM * 2);
  unsigned short* Wb1  = (unsigned short*)take((size_t)E_NUM * H_DIM * DFF * 2);
  unsigned short* Wb2  = (unsigned short*)take((size_t)E_NUM * H_DIM * DFF * 2);
  if (off > ws_size) return;   // ~120 MB; r10/r12 proved >=132 MB available

  int* counts  = ctrl;
  int* offsets = ctrl + 8;

  // prep: route || T1 || T2 in one launch: 512 + 1152 + 1152 = 2816 blocks
  k_prep<<<T_NUM / 4 + 2 * E_NUM * (H_DIM / 128) * (DFF / 128), 256, 0, stream>>>(
      x, Wg, bg, eidx, ew, W1, Wb1, W2, Wb2);
  k_build<<<1, 256, 0, stream>>>(eidx, counts, offsets, tok_of, slot_of);
  k_gather<<<PAIRS / 16, 256, 0, stream>>>(x, tok_of, Xg);

  // GEMM1: 24 nt * 8 e * 6 mt = 1152 blocks (MT_MAX=6 covers Me<=768, 12-sigma)
  k_gemm<H_DIM, DFF / 128, 1, 6, true><<<(DFF / 128) * E_NUM * 6, 256, 0, stream>>>(
      Xg, Wb1, b1, Hmid, counts, offsets);

  // GEMM2: split-K=2, MT_MAX=6 -> 6 nt * 8 e * 2 part * 6 mt = 576 blocks
  k_gemm<DFF, H_DIM / 128, 2, 6, false><<<(H_DIM / 128) * E_NUM * 2 * 6, 256, 0, stream>>>(
      Hmid, Wb2, b2, P, counts, offsets);
  k_combine<2><<<T_NUM, 192, 0, stream>>>(P, slot_of, eidx, ew, b2, out);
}